// Round 17
// baseline (69.875 us; speedup 1.0000x reference)
//
#include <hip/hip_runtime.h>

#define NB 16     // batch
#define CD 128    // channels
#define HW 4096   // spatial L
#define DD 512    // projected dim
#define KC 64     // clusters

typedef __attribute__((ext_vector_type(8))) short bfrag;           // 8 bf16 (4 VGPR)
typedef __attribute__((ext_vector_type(4))) float facc;            // MFMA acc

__device__ __forceinline__ unsigned short f2bf(float f) {
  union { float f; unsigned u; } v; v.f = f;
  unsigned r = v.u + 0x7fffu + ((v.u >> 16) & 1u);   // RNE
  return (unsigned short)(r >> 16);
}
__device__ __forceinline__ float bf2f(unsigned short h) {
  union { unsigned u; float f; } v; v.u = ((unsigned)h) << 16; return v.f;
}
// packed f32x2 -> bf16x2 (RNE), low16 = lo
__device__ __forceinline__ unsigned f2bf2(float lo, float hi) {
  unsigned r;
  asm("v_cvt_pk_bf16_f32 %0, %1, %2" : "=v"(r) : "v"(lo), "v"(hi));
  return r;
}
// async global->LDS: HW writes lds_base + lane*16; global src carries per-lane offset
__device__ __forceinline__ void gll16(const void* g, void* l) {
  __builtin_amdgcn_global_load_lds(
      (__attribute__((address_space(1))) void*)(uintptr_t)g,
      (__attribute__((address_space(3))) void*)(uintptr_t)l, 16, 0, 0);
}
// row swizzle: spreads row-parallel accesses across 8 16B slots
__device__ __forceinline__ int swzr(int r) { return ((r & 7) ^ ((r >> 3) & 7)) << 4; }

// ---------- prep: pre-swizzled W / normalized-centroid LDS images ----------
// Wsw:  8 images x [64d x 256B], byte = dch*16384 + dl*256 + ((c*2)^swzr(dl))
// Cbsw: 8 images x [64k x 128B], byte = dch*8192  + k*128  + ((dl*2)^swzr(k))
__global__ __launch_bounds__(256) void k_prep(const float* __restrict__ conv_w,
                                              const float* __restrict__ centroids,
                                              unsigned short* __restrict__ Wsw,
                                              unsigned short* __restrict__ Cbsw) {
  int b = blockIdx.x, t = threadIdx.x;
  if (b < KC) {
    const float* row = centroids + (size_t)b * DD;
    float v0 = row[t], v1 = row[t + 256];
    float ss = v0 * v0 + v1 * v1;
    #pragma unroll
    for (int off = 32; off; off >>= 1) ss += __shfl_xor(ss, off);
    __shared__ float red[4];
    if ((t & 63) == 0) red[t >> 6] = ss;
    __syncthreads();
    float tot = red[0] + red[1] + red[2] + red[3];
    float inv = 1.0f / fmaxf(sqrtf(tot), 1e-12f);
    int d0 = t, d1 = t + 256;
    *(unsigned short*)((char*)Cbsw + (d0 >> 6) * 8192 + b * 128 +
                       (((d0 & 63) * 2) ^ swzr(b))) = f2bf(v0 * inv);
    *(unsigned short*)((char*)Cbsw + (d1 >> 6) * 8192 + b * 128 +
                       (((d1 & 63) * 2) ^ swzr(b))) = f2bf(v1 * inv);
  } else {
    int i = (b - KC) * 2048 + t * 8;            // 32 blocks cover 512x128
    const float4* src = (const float4*)(conv_w + i);
    float4 a = src[0], c4 = src[1];
    int d = i >> 7, c0 = i & 127;
    int dch = d >> 6, dl = d & 63;
    uint4 w;
    w.x = f2bf2(a.x, a.y);   w.y = f2bf2(a.z, a.w);
    w.z = f2bf2(c4.x, c4.y); w.w = f2bf2(c4.z, c4.w);
    *(uint4*)((char*)Wsw + dch * 16384 + dl * 256 + ((c0 * 2) ^ swzr(dl))) = w;
  }
}

// ---------- fused xnorm + projection + logits/exp (57.5KB LDS -> 2 blocks/CU) ----------
// 8 d-chunks of 64. LDS map (58880 B):
//   [0,16K)      Xraw rows 0-63   / fbuf (128l x 128B)
//   [16K,32K)    Xraw rows 64-127 / etile (2 img x [64k x 128B])
//   [32K,48K)    Ws (64d x 256B, staged image)
//   [48K,56K)    Cbs (64k x 128B, staged image)
//   [56K,+512)   invb[128] ; [+512,+1.5K) ps[64][4]
__global__ __launch_bounds__(512, 2) void k_xproj(const float* __restrict__ x,
                                                  const unsigned short* __restrict__ Wsw,
                                                  const unsigned short* __restrict__ Cbsw,
                                                  const float* __restrict__ conv_b,
                                                  unsigned short* __restrict__ fT,
                                                  unsigned short* __restrict__ eg,
                                                  float* __restrict__ psums) {
  __shared__ __align__(16) char smem[58880];
  char* Xraw  = smem;                     // 128l x 256B: l*256 + ((c*2)^swzr(l))
  char* fbuf  = smem;                     // 128l x 128B (aliases Xraw lo, dead after hoist)
  char* etile = smem + 16384;             // aliases Xraw hi
  char* Ws    = smem + 32768;             // 64d x 256B
  char* Cbs   = smem + 49152;             // 64k x 128B
  float* invb = (float*)(smem + 57344);   // [128]
  float* ps   = (float*)(smem + 57856);   // [64][4]
  int n = blockIdx.y, lblk = blockIdx.x, l0 = lblk * 128;
  int t = threadIdx.x, lane = t & 63, wid = t >> 6;

  // prologue: stage Ws(0) + Cbs(0) (drained at B-P1)
  #pragma unroll
  for (int q = 0; q < 2; q++)
    gll16((const char*)Wsw + (q * 8 + wid) * 1024 + lane * 16, Ws + (q * 8 + wid) * 1024);
  gll16((const char*)Cbsw + wid * 1024 + lane * 16, Cbs + wid * 1024);

  // P1: x fp32 (c-pair rows) -> bf16 -> Xraw (l,c), u32 pair-writes
  #pragma unroll
  for (int j = 0; j < 2; j++) {
    int c0 = ((t >> 4) + 32 * j) * 2;
    const float4* r0p = (const float4*)(x + ((size_t)n * CD + c0) * HW + l0);
    const float4* r1p = (const float4*)(x + ((size_t)n * CD + c0 + 1) * HW + l0);
    #pragma unroll
    for (int jj = 0; jj < 2; jj++) {
      int f4 = (t & 15) + 16 * jj;
      float4 a = r0p[f4], b = r1p[f4];
      int lb = f4 * 4;
      *(unsigned*)(Xraw + (lb + 0) * 256 + ((c0 * 2) ^ swzr(lb + 0))) = f2bf2(a.x, b.x);
      *(unsigned*)(Xraw + (lb + 1) * 256 + ((c0 * 2) ^ swzr(lb + 1))) = f2bf2(a.y, b.y);
      *(unsigned*)(Xraw + (lb + 2) * 256 + ((c0 * 2) ^ swzr(lb + 2))) = f2bf2(a.z, b.z);
      *(unsigned*)(Xraw + (lb + 3) * 256 + ((c0 * 2) ^ swzr(lb + 3))) = f2bf2(a.w, b.w);
    }
  }
  __syncthreads();                        // B-P1: Xraw ready; prologue stages drained

  // P2: inv[l] from row sums (b128 reads; XOR permutation is sum-invariant)
  {
    int l = t >> 2;
    float ss = 0.f;
    #pragma unroll
    for (int p = 0; p < 4; p++) {
      int s16 = (t & 3) + 4 * p;
      bfrag v = *(const bfrag*)(Xraw + l * 256 + ((s16 * 16) ^ swzr(l)));
      #pragma unroll
      for (int i = 0; i < 8; i++) { float f = bf2f((unsigned short)v[i]); ss += f * f; }
    }
    ss += __shfl_xor(ss, 1); ss += __shfl_xor(ss, 2);
    if ((t & 3) == 0) invb[l] = 1.0f / fmaxf(sqrtf(ss), 1e-12f);
  }
  __syncthreads();                        // B-P2: invb ready

  int wd = wid & 1, wl = wid >> 1;        // f waves: 2(d-grp of 32) x 4(l-grp of 32)
  int er = wid >> 2, ec = wid & 3;        // e waves: 2(k-grp of 32) x 4(l-grp of 32)
  int r0 = (lane >> 4) << 2, cl = lane & 15;
  int hi8 = (lane >> 4) << 3;

  // hoist Xraw B-fragments (dch-invariant, 32 VGPR) + per-l-frag inv
  bfrag bfh[4][2];
  #pragma unroll
  for (int kk = 0; kk < 4; kk++)
    #pragma unroll
    for (int j = 0; j < 2; j++) {
      int row = wl * 32 + j * 16 + cl;
      int c0e = kk * 32 + hi8;
      bfh[kk][j] = *(const bfrag*)(Xraw + row * 256 + ((c0e * 2) ^ swzr(row)));
    }
  float hinv[2];
  #pragma unroll
  for (int j = 0; j < 2; j++) hinv[j] = invb[wl * 32 + j * 16 + cl];
  __syncthreads();                        // B-H: Xraw dead -> fbuf/etile regions usable

  facc zero = {0.f, 0.f, 0.f, 0.f};
  facc e_acc[2][2];
  e_acc[0][0] = zero; e_acc[0][1] = zero; e_acc[1][0] = zero; e_acc[1][1] = zero;

  for (int dch = 0; dch < 8; dch++) {
    // iter top: stage Cbs(dch) for dch>=1 (drains at B_mid; prev reads done at B_top)
    if (dch > 0)
      gll16((const char*)Cbsw + dch * 8192 + wid * 1024 + lane * 16, Cbs + wid * 1024);
    // f-MFMA: D[d][l], wave tile 32d x 32l (A=Ws d-rows, B=Xraw hoisted)
    facc acc[2][2];
    acc[0][0] = zero; acc[0][1] = zero; acc[1][0] = zero; acc[1][1] = zero;
    #pragma unroll
    for (int kk = 0; kk < 4; kk++) {
      int c0e = kk * 32 + hi8;
      bfrag am[2];
      #pragma unroll
      for (int m = 0; m < 2; m++) {
        int d = wd * 32 + m * 16 + cl;
        am[m] = *(const bfrag*)(Ws + d * 256 + ((c0e * 2) ^ swzr(d)));
      }
      #pragma unroll
      for (int m = 0; m < 2; m++)
        #pragma unroll
        for (int j = 0; j < 2; j++)
          acc[m][j] = __builtin_amdgcn_mfma_f32_16x16x32_bf16(am[m], bfh[kk][j], acc[m][j], 0, 0, 0);
    }
    // epilogue: f = inv[l]*acc + bias -> fbuf(l,d64); quad spans d -> b64 writes
    #pragma unroll
    for (int m = 0; m < 2; m++) {
      int d0 = wd * 32 + m * 16 + r0;
      float4 bq = *(const float4*)(conv_b + dch * 64 + d0);
      #pragma unroll
      for (int j = 0; j < 2; j++) {
        int l = wl * 32 + j * 16 + cl;
        uint2 w;
        w.x = f2bf2(acc[m][j][0] * hinv[j] + bq.x, acc[m][j][1] * hinv[j] + bq.y);
        w.y = f2bf2(acc[m][j][2] * hinv[j] + bq.z, acc[m][j][3] * hinv[j] + bq.w);
        *(uint2*)(fbuf + l * 128 + ((d0 * 2) ^ swzr(l))) = w;
      }
    }
    __syncthreads();                      // B_mid: fbuf + Cbs(dch) visible; Ws reads done
    // issue Ws(dch+1) (overwrite safe: f reads done; drains at B_top)
    if (dch < 7) {
      #pragma unroll
      for (int q = 0; q < 2; q++)
        gll16((const char*)Wsw + (dch + 1) * 16384 + (q * 8 + wid) * 1024 + lane * 16,
              Ws + (q * 8 + wid) * 1024);
    }
    // coalesced fT dump (stores overlap e-MFMA)
    {
      #pragma unroll
      for (int p = 0; p < 2; p++) {
        int ch = p * 512 + t;
        int lr = ch >> 3, c16 = ch & 7;
        bfrag v = *(const bfrag*)(fbuf + lr * 128 + ((c16 * 16) ^ swzr(lr)));
        *(bfrag*)(fT + ((size_t)n * HW + l0 + lr) * DD + dch * 64 + c16 * 8) = v;
      }
    }
    // e-MFMA: e_acc += Cbs(64k x 64d) x fbuf(128l x 64d)^T, wave tile 32k x 32l
    #pragma unroll
    for (int kk = 0; kk < 2; kk++) {
      int d0 = kk * 32 + hi8;
      bfrag ca[2], fb[2];
      #pragma unroll
      for (int m2 = 0; m2 < 2; m2++) {
        int k2 = er * 32 + m2 * 16 + cl;
        ca[m2] = *(const bfrag*)(Cbs + k2 * 128 + ((d0 * 2) ^ swzr(k2)));
      }
      #pragma unroll
      for (int j2 = 0; j2 < 2; j2++) {
        int l2 = ec * 32 + j2 * 16 + cl;
        fb[j2] = *(const bfrag*)(fbuf + l2 * 128 + ((d0 * 2) ^ swzr(l2)));
      }
      #pragma unroll
      for (int m2 = 0; m2 < 2; m2++)
        #pragma unroll
        for (int j2 = 0; j2 < 2; j2++)
          e_acc[m2][j2] = __builtin_amdgcn_mfma_f32_16x16x32_bf16(ca[m2], fb[j2], e_acc[m2][j2], 0, 0, 0);
    }
    __syncthreads();                      // B_top: Ws stage drained; fbuf/Cbs reads done
  }

  // P5: exp -> etile + rowsum partials
  {
    int l2base = ec * 32;
    #pragma unroll
    for (int m2 = 0; m2 < 2; m2++) {
      #pragma unroll
      for (int q = 0; q < 4; q++) {
        int k2 = er * 32 + m2 * 16 + r0 + q;
        float vsum = 0.f;
        #pragma unroll
        for (int j2 = 0; j2 < 2; j2++) {
          int l2 = l2base + j2 * 16 + cl;
          float ev = __expf(e_acc[m2][j2][q]);
          *(unsigned short*)(etile + (l2 >> 6) * 8192 + k2 * 128 +
                             (((l2 & 63) * 2) ^ swzr(k2))) = f2bf(ev);
          vsum += ev;
        }
        vsum += __shfl_xor(vsum, 1); vsum += __shfl_xor(vsum, 2);
        vsum += __shfl_xor(vsum, 4); vsum += __shfl_xor(vsum, 8);
        if (cl == 0) ps[k2 * 4 + ec] = vsum;
      }
    }
  }
  __syncthreads();
  // dump 2 e-images (16K contiguous) + psums
  {
    size_t base = ((size_t)n * 64 + lblk * 2) * 8192;
    #pragma unroll
    for (int p = 0; p < 2; p++) {
      uint4 v = *(const uint4*)(etile + (t + p * 512) * 16);
      *(uint4*)((char*)eg + base + (t + p * 512) * 16) = v;
    }
  }
  if (t < 64) {
    float4 v = ((const float4*)ps)[t];
    psums[((size_t)n * 32 + lblk) * 64 + t] = v.x + v.y + v.z + v.w;
  }
}

// ---------- vlad partials: part[sk,n,k,d] = sum_l e[n,k,l] f[n,l,d] ----------
__global__ __launch_bounds__(256) void k_vlad(const unsigned short* __restrict__ eg,
                                              const unsigned short* __restrict__ fT,
                                              float* __restrict__ part) {
  __shared__ __align__(16) char smem[49152];
  char* As = smem;            // 2 images x [64k x 128B]: k*128 + ((l''*2)^swzr(k))
  char* Bs = smem + 16384;    // [128d][128l]: d*256 + ((l*2)^(((d&7)^((d>>3)&7))<<4))
  int t = threadIdx.x, lane = t & 63, wid = t >> 6;
  int wr = wid >> 1, wc = wid & 1;
  int lin = blockIdx.x;
  int xcd = lin & 7, jj = lin >> 3;
  int grp = xcd * 8 + (jj >> 2);                // 0..63 = (n,sk)
  int dt = jj & 3, n = grp >> 2, sk = grp & 3;
  int dbase = dt * 128;
  facc acc[2][4];
  facc zero = {0.f, 0.f, 0.f, 0.f};
  #pragma unroll
  for (int m = 0; m < 2; m++)
    #pragma unroll
    for (int j = 0; j < 4; j++) acc[m][j] = zero;

  for (int ks = 0; ks < 8; ks++) {
    int l0 = sk * 1024 + ks * 128;
    {   // stage A: two consecutive 8K e-images via gll16
      const char* easrc = (const char*)eg + ((size_t)n * 64 + (l0 >> 6)) * 8192;
      #pragma unroll
      for (int q = 0; q < 4; q++)
        gll16(easrc + (q * 4 + wid) * 1024 + lane * 16, As + (q * 4 + wid) * 1024);
    }
    // stage B transposed (fT rows l -> Bs[d][l])
    #pragma unroll
    for (int q = 0; q < 8; q++) {
      int ch = q * 256 + t;
      int l = ch >> 4, dc = ch & 15;
      bfrag v = *(const bfrag*)(fT + ((size_t)n * HW + l0 + l) * DD + dbase + dc * 8);
      #pragma unroll
      for (int i = 0; i < 8; i++) {
        int d = dc * 8 + i;
        int swz = (((d & 7) ^ ((d >> 3) & 7)) << 4);
        *(unsigned short*)(Bs + d * 256 + ((l * 2) ^ swz)) = (unsigned short)v[i];
      }
    }
    __syncthreads();
    #pragma unroll
    for (int kk = 0; kk < 128; kk += 32) {
      int lk = kk + ((lane >> 4) << 3);
      const char* Ai = As + (kk >> 6) * 8192;
      int ll = lk & 63;
      bfrag af[2], bf[4];
      #pragma unroll
      for (int m = 0; m < 2; m++) {
        int krow = wr * 32 + m * 16 + (lane & 15);
        af[m] = *(const bfrag*)(Ai + krow * 128 + ((ll * 2) ^ swzr(krow)));
      }
      #pragma unroll
      for (int j = 0; j < 4; j++) {
        int d = wc * 64 + j * 16 + (lane & 15);
        int swz = (((d & 7) ^ ((d >> 3) & 7)) << 4);
        bf[j] = *(const bfrag*)(Bs + d * 256 + ((lk * 2) ^ swz));
      }
      #pragma unroll
      for (int m = 0; m < 2; m++)
        #pragma unroll
        for (int j = 0; j < 4; j++)
          acc[m][j] = __builtin_amdgcn_mfma_f32_16x16x32_bf16(af[m], bf[j], acc[m][j], 0, 0, 0);
    }
    __syncthreads();
  }
  int r0 = (lane >> 4) << 2, cl = lane & 15;
  size_t base = ((size_t)(sk * NB + n)) * (KC * DD);
  #pragma unroll
  for (int m = 0; m < 2; m++) {
    int krow = wr * 32 + m * 16 + r0;
    #pragma unroll
    for (int j = 0; j < 4; j++) {
      int d = dbase + wc * 64 + j * 16 + cl;
      #pragma unroll
      for (int q = 0; q < 4; q++)
        part[base + (size_t)(krow + q) * DD + d] = acc[m][j][q];
    }
  }
}

// ---------- reduce split-K partials (4), compute rinv inline, normalize ----------
__global__ __launch_bounds__(256) void k_reduce(const float* __restrict__ part,
                                                const float* __restrict__ psums,
                                                float* __restrict__ out) {
  int b = blockIdx.x, t = threadIdx.x;
  int nk = b >> 1;                              // constant per block
  int n = nk >> 6, k = nk & 63;
  __shared__ float rsh;
  if (t < 32) {
    float s = psums[((size_t)n * 32 + t) * 64 + k];
    #pragma unroll
    for (int off = 16; off; off >>= 1) s += __shfl_xor(s, off, 32);
    if (t == 0) rsh = 1.0f / s;
  }
  __syncthreads();
  float rinv = rsh;
  int i = b * 256 + t;
  float s = 0.f;
  #pragma unroll
  for (int skk = 0; skk < 4; skk++) s += part[(size_t)skk * (NB * KC * DD) + i];
  out[i] = s * rinv;
}

extern "C" void kernel_launch(void* const* d_in, const int* in_sizes, int n_in,
                              void* d_out, int out_size, void* d_ws, size_t ws_size,
                              hipStream_t stream) {
  const float* x         = (const float*)d_in[0];
  const float* conv_w    = (const float*)d_in[1];
  const float* conv_b    = (const float*)d_in[2];
  const float* centroids = (const float*)d_in[3];
  float* out = (float*)d_out;
  char* ws = (char*)d_ws;

  // ws layout (bytes):
  //   Wsw   @ 0          (128 KB)   conv_w bf16, 8x16K pre-swizzled images
  //   Cbsw  @ 131072     (64 KB)    normalized centroids bf16, 8x8K images
  //   fT    @ 196608     (64 MB)    f bf16 (N,L,D)
  //   eg    @ 67305472   (8 MB)     exp(logits) bf16, N*64 x 8K images
  //   psums @ 75694080   (128 KB)   per-tile row sums fp32 (N,32,K)
  //   part  @ 75960320   (8 MB)     vlad partials fp32 (4,N,K,D)
  unsigned short* Wsw  = (unsigned short*)(ws);
  unsigned short* Cbsw = (unsigned short*)(ws + 131072);
  unsigned short* fT   = (unsigned short*)(ws + 196608);
  unsigned short* eg   = (unsigned short*)(ws + 67305472ull);
  float*          psums= (float*)(ws + 75694080ull);
  float*          part = (float*)(ws + 75960320ull);

  k_prep<<<dim3(96), dim3(256), 0, stream>>>(conv_w, centroids, Wsw, Cbsw);

  // fused xnorm + projection + logits/exp -> fT, e-images, psums
  k_xproj<<<dim3(32, NB), dim3(512), 0, stream>>>(x, Wsw, Cbsw, conv_b, fT, eg, psums);

  // vlad partials: e(K,L) * f(L,D), split-L into 4 chunks of 1024
  k_vlad<<<dim3(256), dim3(256), 0, stream>>>(eg, fT, part);

  k_reduce<<<dim3(NB * KC * DD / 256), dim3(256), 0, stream>>>(part, psums, out);

  (void)in_sizes; (void)n_in; (void)out_size; (void)ws_size;
}

// Round 18
// 58.397 us; speedup vs baseline: 1.1965x; 1.1965x over previous
//
#include <hip/hip_runtime.h>

#define NB 16     // batch
#define CD 128    // channels
#define HW 4096   // spatial L
#define DD 512    // projected dim
#define KC 64     // clusters

typedef __attribute__((ext_vector_type(8))) short bfrag;           // 8 bf16 (4 VGPR)
typedef __attribute__((ext_vector_type(4))) float facc;            // MFMA acc

__device__ __forceinline__ unsigned short f2bf(float f) {
  union { float f; unsigned u; } v; v.f = f;
  unsigned r = v.u + 0x7fffu + ((v.u >> 16) & 1u);   // RNE
  return (unsigned short)(r >> 16);
}
__device__ __forceinline__ float bf2f(unsigned short h) {
  union { unsigned u; float f; } v; v.u = ((unsigned)h) << 16; return v.f;
}
// packed f32x2 -> bf16x2 (RNE), low16 = lo
__device__ __forceinline__ unsigned f2bf2(float lo, float hi) {
  unsigned r;
  asm("v_cvt_pk_bf16_f32 %0, %1, %2" : "=v"(r) : "v"(lo), "v"(hi));
  return r;
}
// async global->LDS: HW writes lds_base + lane*16; global src carries per-lane offset
__device__ __forceinline__ void gll16(const void* g, void* l) {
  __builtin_amdgcn_global_load_lds(
      (__attribute__((address_space(1))) void*)(uintptr_t)g,
      (__attribute__((address_space(3))) void*)(uintptr_t)l, 16, 0, 0);
}
// row swizzle: spreads row-parallel accesses across 8 16B slots
__device__ __forceinline__ int swzr(int r) { return ((r & 7) ^ ((r >> 3) & 7)) << 4; }

// ---------- prep: pre-swizzled W / normalized-centroid LDS images ----------
// Wsw:  8 images x [64d x 256B], byte = dch*16384 + dl*256 + ((c*2)^swzr(dl))
// Cbsw: 8 images x [64k x 128B], byte = dch*8192  + k*128  + ((dl*2)^swzr(k))
__global__ __launch_bounds__(256) void k_prep(const float* __restrict__ conv_w,
                                              const float* __restrict__ centroids,
                                              unsigned short* __restrict__ Wsw,
                                              unsigned short* __restrict__ Cbsw) {
  int b = blockIdx.x, t = threadIdx.x;
  if (b < KC) {
    const float* row = centroids + (size_t)b * DD;
    float v0 = row[t], v1 = row[t + 256];
    float ss = v0 * v0 + v1 * v1;
    #pragma unroll
    for (int off = 32; off; off >>= 1) ss += __shfl_xor(ss, off);
    __shared__ float red[4];
    if ((t & 63) == 0) red[t >> 6] = ss;
    __syncthreads();
    float tot = red[0] + red[1] + red[2] + red[3];
    float inv = 1.0f / fmaxf(sqrtf(tot), 1e-12f);
    int d0 = t, d1 = t + 256;
    *(unsigned short*)((char*)Cbsw + (d0 >> 6) * 8192 + b * 128 +
                       (((d0 & 63) * 2) ^ swzr(b))) = f2bf(v0 * inv);
    *(unsigned short*)((char*)Cbsw + (d1 >> 6) * 8192 + b * 128 +
                       (((d1 & 63) * 2) ^ swzr(b))) = f2bf(v1 * inv);
  } else {
    int i = (b - KC) * 2048 + t * 8;            // 32 blocks cover 512x128
    const float4* src = (const float4*)(conv_w + i);
    float4 a = src[0], c4 = src[1];
    int d = i >> 7, c0 = i & 127;
    int dch = d >> 6, dl = d & 63;
    uint4 w;
    w.x = f2bf2(a.x, a.y);   w.y = f2bf2(a.z, a.w);
    w.z = f2bf2(c4.x, c4.y); w.w = f2bf2(c4.z, c4.w);
    *(uint4*)((char*)Wsw + dch * 16384 + dl * 256 + ((c0 * 2) ^ swzr(dl))) = w;
  }
}

// ---------- fused xnorm + projection + logits/exp — counted-vmcnt loop ----------
// 8 d-chunks of 64. LDS map (67072 B, 2 blocks/CU):
//   [0,16K)    Xraw rows 0-63   / fbuf (128l x 128B)
//   [16K,32K)  Xraw rows 64-127 / etile (2 img x [64k x 128B])
//   [32K,48K)  Ws (64d x 256B, single-buffer staged image)
//   [48K,64K)  Cbs x2 (64k x 128B each, double-buffered)
//   [64K,+512) invb[128] ; [+512,+1.5K) ps[64][4]
// Loop sync (per-wave vmem queue, issue order pinned by sched_barrier):
//   iter top: queue = [Cbs(dch), st(dch-1) x2]
//   B_mid : vmcnt(2)+lgkm0  -> Cbs(dch) drained; fbuf visible; stores stay
//   issue Ws(dch+1) x2, Cbs(dch+1) x1 ; then stores x2 -> queue 7
//   B_top : vmcnt(3)+lgkm0  -> drains [st,st,Ws',Ws']; leaves [Cbs',st,st]
__global__ __launch_bounds__(512, 2) void k_xproj(const float* __restrict__ x,
                                                  const unsigned short* __restrict__ Wsw,
                                                  const unsigned short* __restrict__ Cbsw,
                                                  const float* __restrict__ conv_b,
                                                  unsigned short* __restrict__ fT,
                                                  unsigned short* __restrict__ eg,
                                                  float* __restrict__ psums) {
  __shared__ __align__(16) char smem[67072];
  char* Xraw  = smem;                     // 128l x 256B: l*256 + ((c*2)^swzr(l))
  char* fbuf  = smem;                     // 128l x 128B (aliases Xraw lo, dead after hoist)
  char* etile = smem + 16384;             // aliases Xraw hi
  char* Ws    = smem + 32768;             // 64d x 256B
  char* Cb2   = smem + 49152;             // 2 x (64k x 128B)
  float* invb = (float*)(smem + 65536);   // [128]
  float* ps   = (float*)(smem + 66048);   // [64][4]
  int n = blockIdx.y, lblk = blockIdx.x, l0 = lblk * 128;
  int t = threadIdx.x, lane = t & 63, wid = t >> 6;

  // prologue: stage Ws(0) + Cbs(0)->buf0 (drained at B-P1's full syncthreads)
  #pragma unroll
  for (int q = 0; q < 2; q++)
    gll16((const char*)Wsw + (q * 8 + wid) * 1024 + lane * 16, Ws + (q * 8 + wid) * 1024);
  gll16((const char*)Cbsw + wid * 1024 + lane * 16, Cb2 + wid * 1024);

  // P1: x fp32 (c-pair rows) -> bf16 -> Xraw (l,c), u32 pair-writes
  #pragma unroll
  for (int j = 0; j < 2; j++) {
    int c0 = ((t >> 4) + 32 * j) * 2;
    const float4* r0p = (const float4*)(x + ((size_t)n * CD + c0) * HW + l0);
    const float4* r1p = (const float4*)(x + ((size_t)n * CD + c0 + 1) * HW + l0);
    #pragma unroll
    for (int jj = 0; jj < 2; jj++) {
      int f4 = (t & 15) + 16 * jj;
      float4 a = r0p[f4], b = r1p[f4];
      int lb = f4 * 4;
      *(unsigned*)(Xraw + (lb + 0) * 256 + ((c0 * 2) ^ swzr(lb + 0))) = f2bf2(a.x, b.x);
      *(unsigned*)(Xraw + (lb + 1) * 256 + ((c0 * 2) ^ swzr(lb + 1))) = f2bf2(a.y, b.y);
      *(unsigned*)(Xraw + (lb + 2) * 256 + ((c0 * 2) ^ swzr(lb + 2))) = f2bf2(a.z, b.z);
      *(unsigned*)(Xraw + (lb + 3) * 256 + ((c0 * 2) ^ swzr(lb + 3))) = f2bf2(a.w, b.w);
    }
  }
  __syncthreads();                        // B-P1 (full drain): Xraw ready; stage(0) done

  // P2: inv[l] from row sums (b128 reads; XOR permutation is sum-invariant)
  {
    int l = t >> 2;
    float ss = 0.f;
    #pragma unroll
    for (int p = 0; p < 4; p++) {
      int s16 = (t & 3) + 4 * p;
      bfrag v = *(const bfrag*)(Xraw + l * 256 + ((s16 * 16) ^ swzr(l)));
      #pragma unroll
      for (int i = 0; i < 8; i++) { float f = bf2f((unsigned short)v[i]); ss += f * f; }
    }
    ss += __shfl_xor(ss, 1); ss += __shfl_xor(ss, 2);
    if ((t & 3) == 0) invb[l] = 1.0f / fmaxf(sqrtf(ss), 1e-12f);
  }
  __syncthreads();                        // B-P2: invb ready

  int wd = wid & 1, wl = wid >> 1;        // f waves: 2(d-grp of 32) x 4(l-grp of 32)
  int er = wid >> 2, ec = wid & 3;        // e waves: 2(k-grp of 32) x 4(l-grp of 32)
  int r0 = (lane >> 4) << 2, cl = lane & 15;
  int hi8 = (lane >> 4) << 3;

  // hoist Xraw B-fragments (dch-invariant, 32 VGPR) + per-l-frag inv
  bfrag bfh[4][2];
  #pragma unroll
  for (int kk = 0; kk < 4; kk++)
    #pragma unroll
    for (int j = 0; j < 2; j++) {
      int row = wl * 32 + j * 16 + cl;
      int c0e = kk * 32 + hi8;
      bfh[kk][j] = *(const bfrag*)(Xraw + row * 256 + ((c0e * 2) ^ swzr(row)));
    }
  float hinv[2];
  #pragma unroll
  for (int j = 0; j < 2; j++) hinv[j] = invb[wl * 32 + j * 16 + cl];
  __syncthreads();                        // B-H: Xraw dead -> fbuf/etile usable; queue empty

  facc zero = {0.f, 0.f, 0.f, 0.f};
  facc e_acc[2][2];
  e_acc[0][0] = zero; e_acc[0][1] = zero; e_acc[1][0] = zero; e_acc[1][1] = zero;

  for (int dch = 0; dch < 8; dch++) {
    const char* Cbs = Cb2 + ((dch & 1) << 13);
    // f-MFMA: D[d][l], wave tile 32d x 32l (Ws(dch) guaranteed by prev B_top / prologue)
    facc acc[2][2];
    acc[0][0] = zero; acc[0][1] = zero; acc[1][0] = zero; acc[1][1] = zero;
    #pragma unroll
    for (int kk = 0; kk < 4; kk++) {
      int c0e = kk * 32 + hi8;
      bfrag am[2];
      #pragma unroll
      for (int m = 0; m < 2; m++) {
        int d = wd * 32 + m * 16 + cl;
        am[m] = *(const bfrag*)(Ws + d * 256 + ((c0e * 2) ^ swzr(d)));
      }
      #pragma unroll
      for (int m = 0; m < 2; m++)
        #pragma unroll
        for (int j = 0; j < 2; j++)
          acc[m][j] = __builtin_amdgcn_mfma_f32_16x16x32_bf16(am[m], bfh[kk][j], acc[m][j], 0, 0, 0);
    }
    // epilogue: f = inv[l]*acc + bias -> fbuf(l,d64); quad spans d -> b64 writes
    #pragma unroll
    for (int m = 0; m < 2; m++) {
      int d0 = wd * 32 + m * 16 + r0;
      float4 bq = *(const float4*)(conv_b + dch * 64 + d0);
      #pragma unroll
      for (int j = 0; j < 2; j++) {
        int l = wl * 32 + j * 16 + cl;
        uint2 w;
        w.x = f2bf2(acc[m][j][0] * hinv[j] + bq.x, acc[m][j][1] * hinv[j] + bq.y);
        w.y = f2bf2(acc[m][j][2] * hinv[j] + bq.z, acc[m][j][3] * hinv[j] + bq.w);
        *(uint2*)(fbuf + l * 128 + ((d0 * 2) ^ swzr(l))) = w;
      }
    }
    // B_mid: Cbs(dch) drained + fbuf visible; old stores stay in flight
    asm volatile("s_waitcnt vmcnt(2) lgkmcnt(0)" ::: "memory");
    __builtin_amdgcn_s_barrier();
    __builtin_amdgcn_sched_barrier(0);
    // stage Ws(dch+1) + Cbs(dch+1) (issue order pinned: stages before stores)
    if (dch < 7) {
      #pragma unroll
      for (int q = 0; q < 2; q++)
        gll16((const char*)Wsw + (dch + 1) * 16384 + (q * 8 + wid) * 1024 + lane * 16,
              Ws + (q * 8 + wid) * 1024);
      gll16((const char*)Cbsw + (dch + 1) * 8192 + wid * 1024 + lane * 16,
            Cb2 + (((dch + 1) & 1) << 13) + wid * 1024);
    }
    __builtin_amdgcn_sched_barrier(0);
    // coalesced fT dump (2 b128 ds_reads + 2 global stores; stores drain next iter)
    {
      #pragma unroll
      for (int p = 0; p < 2; p++) {
        int ch = p * 512 + t;
        int lr = ch >> 3, c16 = ch & 7;
        bfrag v = *(const bfrag*)(fbuf + lr * 128 + ((c16 * 16) ^ swzr(lr)));
        *(bfrag*)(fT + ((size_t)n * HW + l0 + lr) * DD + dch * 64 + c16 * 8) = v;
      }
    }
    // e-MFMA: e_acc += Cbs(64k x 64d) x fbuf(128l x 64d)^T, wave tile 32k x 32l
    #pragma unroll
    for (int kk = 0; kk < 2; kk++) {
      int d0 = kk * 32 + hi8;
      bfrag ca[2], fb[2];
      #pragma unroll
      for (int m2 = 0; m2 < 2; m2++) {
        int k2 = er * 32 + m2 * 16 + cl;
        ca[m2] = *(const bfrag*)(Cbs + k2 * 128 + ((d0 * 2) ^ swzr(k2)));
      }
      #pragma unroll
      for (int j2 = 0; j2 < 2; j2++) {
        int l2 = ec * 32 + j2 * 16 + cl;
        fb[j2] = *(const bfrag*)(fbuf + l2 * 128 + ((d0 * 2) ^ swzr(l2)));
      }
      #pragma unroll
      for (int m2 = 0; m2 < 2; m2++)
        #pragma unroll
        for (int j2 = 0; j2 < 2; j2++)
          e_acc[m2][j2] = __builtin_amdgcn_mfma_f32_16x16x32_bf16(ca[m2], fb[j2], e_acc[m2][j2], 0, 0, 0);
    }
    // B_top: fbuf reads done; Ws(dch+1) drained; stores from this iter stay
    asm volatile("s_waitcnt vmcnt(3) lgkmcnt(0)" ::: "memory");
    __builtin_amdgcn_s_barrier();
    __builtin_amdgcn_sched_barrier(0);
  }

  // P5: exp -> etile + rowsum partials
  {
    int l2base = ec * 32;
    #pragma unroll
    for (int m2 = 0; m2 < 2; m2++) {
      #pragma unroll
      for (int q = 0; q < 4; q++) {
        int k2 = er * 32 + m2 * 16 + r0 + q;
        float vsum = 0.f;
        #pragma unroll
        for (int j2 = 0; j2 < 2; j2++) {
          int l2 = l2base + j2 * 16 + cl;
          float ev = __expf(e_acc[m2][j2][q]);
          *(unsigned short*)(etile + (l2 >> 6) * 8192 + k2 * 128 +
                             (((l2 & 63) * 2) ^ swzr(k2))) = f2bf(ev);
          vsum += ev;
        }
        vsum += __shfl_xor(vsum, 1); vsum += __shfl_xor(vsum, 2);
        vsum += __shfl_xor(vsum, 4); vsum += __shfl_xor(vsum, 8);
        if (cl == 0) ps[k2 * 4 + ec] = vsum;
      }
    }
  }
  __syncthreads();                        // full drain before final dumps
  // dump 2 e-images (16K contiguous) + psums
  {
    size_t base = ((size_t)n * 64 + lblk * 2) * 8192;
    #pragma unroll
    for (int p = 0; p < 2; p++) {
      uint4 v = *(const uint4*)(etile + (t + p * 512) * 16);
      *(uint4*)((char*)eg + base + (t + p * 512) * 16) = v;
    }
  }
  if (t < 64) {
    float4 v = ((const float4*)ps)[t];
    psums[((size_t)n * 32 + lblk) * 64 + t] = v.x + v.y + v.z + v.w;
  }
}

// ---------- vlad partials: part[sk,n,k,d] = sum_l e[n,k,l] f[n,l,d] ----------
__global__ __launch_bounds__(256) void k_vlad(const unsigned short* __restrict__ eg,
                                              const unsigned short* __restrict__ fT,
                                              float* __restrict__ part) {
  __shared__ __align__(16) char smem[49152];
  char* As = smem;            // 2 images x [64k x 128B]: k*128 + ((l''*2)^swzr(k))
  char* Bs = smem + 16384;    // [128d][128l]: d*256 + ((l*2)^(((d&7)^((d>>3)&7))<<4))
  int t = threadIdx.x, lane = t & 63, wid = t >> 6;
  int wr = wid >> 1, wc = wid & 1;
  int lin = blockIdx.x;
  int xcd = lin & 7, jj = lin >> 3;
  int grp = xcd * 8 + (jj >> 2);                // 0..63 = (n,sk)
  int dt = jj & 3, n = grp >> 2, sk = grp & 3;
  int dbase = dt * 128;
  facc acc[2][4];
  facc zero = {0.f, 0.f, 0.f, 0.f};
  #pragma unroll
  for (int m = 0; m < 2; m++)
    #pragma unroll
    for (int j = 0; j < 4; j++) acc[m][j] = zero;

  for (int ks = 0; ks < 8; ks++) {
    int l0 = sk * 1024 + ks * 128;
    {   // stage A: two consecutive 8K e-images via gll16
      const char* easrc = (const char*)eg + ((size_t)n * 64 + (l0 >> 6)) * 8192;
      #pragma unroll
      for (int q = 0; q < 4; q++)
        gll16(easrc + (q * 4 + wid) * 1024 + lane * 16, As + (q * 4 + wid) * 1024);
    }
    // stage B transposed (fT rows l -> Bs[d][l])
    #pragma unroll
    for (int q = 0; q < 8; q++) {
      int ch = q * 256 + t;
      int l = ch >> 4, dc = ch & 15;
      bfrag v = *(const bfrag*)(fT + ((size_t)n * HW + l0 + l) * DD + dbase + dc * 8);
      #pragma unroll
      for (int i = 0; i < 8; i++) {
        int d = dc * 8 + i;
        int swz = (((d & 7) ^ ((d >> 3) & 7)) << 4);
        *(unsigned short*)(Bs + d * 256 + ((l * 2) ^ swz)) = (unsigned short)v[i];
      }
    }
    __syncthreads();
    #pragma unroll
    for (int kk = 0; kk < 128; kk += 32) {
      int lk = kk + ((lane >> 4) << 3);
      const char* Ai = As + (kk >> 6) * 8192;
      int ll = lk & 63;
      bfrag af[2], bf[4];
      #pragma unroll
      for (int m = 0; m < 2; m++) {
        int krow = wr * 32 + m * 16 + (lane & 15);
        af[m] = *(const bfrag*)(Ai + krow * 128 + ((ll * 2) ^ swzr(krow)));
      }
      #pragma unroll
      for (int j = 0; j < 4; j++) {
        int d = wc * 64 + j * 16 + (lane & 15);
        int swz = (((d & 7) ^ ((d >> 3) & 7)) << 4);
        bf[j] = *(const bfrag*)(Bs + d * 256 + ((lk * 2) ^ swz));
      }
      #pragma unroll
      for (int m = 0; m < 2; m++)
        #pragma unroll
        for (int j = 0; j < 4; j++)
          acc[m][j] = __builtin_amdgcn_mfma_f32_16x16x32_bf16(af[m], bf[j], acc[m][j], 0, 0, 0);
    }
    __syncthreads();
  }
  int r0 = (lane >> 4) << 2, cl = lane & 15;
  size_t base = ((size_t)(sk * NB + n)) * (KC * DD);
  #pragma unroll
  for (int m = 0; m < 2; m++) {
    int krow = wr * 32 + m * 16 + r0;
    #pragma unroll
    for (int j = 0; j < 4; j++) {
      int d = dbase + wc * 64 + j * 16 + cl;
      #pragma unroll
      for (int q = 0; q < 4; q++)
        part[base + (size_t)(krow + q) * DD + d] = acc[m][j][q];
    }
  }
}

// ---------- reduce split-K partials (4), compute rinv inline, normalize ----------
__global__ __launch_bounds__(256) void k_reduce(const float* __restrict__ part,
                                                const float* __restrict__ psums,
                                                float* __restrict__ out) {
  int b = blockIdx.x, t = threadIdx.x;
  int nk = b >> 1;                              // constant per block
  int n = nk >> 6, k = nk & 63;
  __shared__ float rsh;
  if (t < 32) {
    float s = psums[((size_t)n * 32 + t) * 64 + k];
    #pragma unroll
    for (int off = 16; off; off >>= 1) s += __shfl_xor(s, off, 32);
    if (t == 0) rsh = 1.0f / s;
  }
  __syncthreads();
  float rinv = rsh;
  int i = b * 256 + t;
  float s = 0.f;
  #pragma unroll
  for (int skk = 0; skk < 4; skk++) s += part[(size_t)skk * (NB * KC * DD) + i];
  out[i] = s * rinv;
}

extern "C" void kernel_launch(void* const* d_in, const int* in_sizes, int n_in,
                              void* d_out, int out_size, void* d_ws, size_t ws_size,
                              hipStream_t stream) {
  const float* x         = (const float*)d_in[0];
  const float* conv_w    = (const float*)d_in[1];
  const float* conv_b    = (const float*)d_in[2];
  const float* centroids = (const float*)d_in[3];
  float* out = (float*)d_out;
  char* ws = (char*)d_ws;

  // ws layout (bytes):
  //   Wsw   @ 0          (128 KB)   conv_w bf16, 8x16K pre-swizzled images
  //   Cbsw  @ 131072     (64 KB)    normalized centroids bf16, 8x8K images
  //   fT    @ 196608     (64 MB)    f bf16 (N,L,D)
  //   eg    @ 67305472   (8 MB)     exp(logits) bf16, N*64 x 8K images
  //   psums @ 75694080   (128 KB)   per-tile row sums fp32 (N,32,K)
  //   part  @ 75960320   (8 MB)     vlad partials fp32 (4,N,K,D)
  unsigned short* Wsw  = (unsigned short*)(ws);
  unsigned short* Cbsw = (unsigned short*)(ws + 131072);
  unsigned short* fT   = (unsigned short*)(ws + 196608);
  unsigned short* eg   = (unsigned short*)(ws + 67305472ull);
  float*          psums= (float*)(ws + 75694080ull);
  float*          part = (float*)(ws + 75960320ull);

  k_prep<<<dim3(96), dim3(256), 0, stream>>>(conv_w, centroids, Wsw, Cbsw);

  // fused xnorm + projection + logits/exp -> fT, e-images, psums
  k_xproj<<<dim3(32, NB), dim3(512), 0, stream>>>(x, Wsw, Cbsw, conv_b, fT, eg, psums);

  // vlad partials: e(K,L) * f(L,D), split-L into 4 chunks of 1024
  k_vlad<<<dim3(256), dim3(256), 0, stream>>>(eg, fT, part);

  k_reduce<<<dim3(NB * KC * DD / 256), dim3(256), 0, stream>>>(part, psums, out);

  (void)in_sizes; (void)n_in; (void)out_size; (void)ws_size;
}

// Round 19
// 54.757 us; speedup vs baseline: 1.2761x; 1.0665x over previous
//
#include <hip/hip_runtime.h>

#define NB 16     // batch
#define CD 128    // channels
#define HW 4096   // spatial L
#define DD 512    // projected dim
#define KC 64     // clusters

typedef __attribute__((ext_vector_type(8))) short bfrag;           // 8 bf16 (4 VGPR)
typedef __attribute__((ext_vector_type(4))) float facc;            // MFMA acc

__device__ __forceinline__ unsigned short f2bf(float f) {
  union { float f; unsigned u; } v; v.f = f;
  unsigned r = v.u + 0x7fffu + ((v.u >> 16) & 1u);   // RNE
  return (unsigned short)(r >> 16);
}
__device__ __forceinline__ float bf2f(unsigned short h) {
  union { unsigned u; float f; } v; v.u = ((unsigned)h) << 16; return v.f;
}
// packed f32x2 -> bf16x2 (RNE), low16 = lo
__device__ __forceinline__ unsigned f2bf2(float lo, float hi) {
  unsigned r;
  asm("v_cvt_pk_bf16_f32 %0, %1, %2" : "=v"(r) : "v"(lo), "v"(hi));
  return r;
}
// async global->LDS: HW writes lds_base + lane*16; global src carries per-lane offset
__device__ __forceinline__ void gll16(const void* g, void* l) {
  __builtin_amdgcn_global_load_lds(
      (__attribute__((address_space(1))) void*)(uintptr_t)g,
      (__attribute__((address_space(3))) void*)(uintptr_t)l, 16, 0, 0);
}
// row swizzle: spreads row-parallel accesses across 8 16B slots
__device__ __forceinline__ int swzr(int r) { return ((r & 7) ^ ((r >> 3) & 7)) << 4; }

// ---------- prep: pre-swizzled W / normalized-centroid LDS images ----------
// Wsw:  8 images x [64d x 256B], byte = dch*16384 + dl*256 + ((c*2)^swzr(dl))
// Cbsw: 8 images x [64k x 128B], byte = dch*8192  + k*128  + ((dl*2)^swzr(k))
__global__ __launch_bounds__(256) void k_prep(const float* __restrict__ conv_w,
                                              const float* __restrict__ centroids,
                                              unsigned short* __restrict__ Wsw,
                                              unsigned short* __restrict__ Cbsw) {
  int b = blockIdx.x, t = threadIdx.x;
  if (b < KC) {
    const float* row = centroids + (size_t)b * DD;
    float v0 = row[t], v1 = row[t + 256];
    float ss = v0 * v0 + v1 * v1;
    #pragma unroll
    for (int off = 32; off; off >>= 1) ss += __shfl_xor(ss, off);
    __shared__ float red[4];
    if ((t & 63) == 0) red[t >> 6] = ss;
    __syncthreads();
    float tot = red[0] + red[1] + red[2] + red[3];
    float inv = 1.0f / fmaxf(sqrtf(tot), 1e-12f);
    int d0 = t, d1 = t + 256;
    *(unsigned short*)((char*)Cbsw + (d0 >> 6) * 8192 + b * 128 +
                       (((d0 & 63) * 2) ^ swzr(b))) = f2bf(v0 * inv);
    *(unsigned short*)((char*)Cbsw + (d1 >> 6) * 8192 + b * 128 +
                       (((d1 & 63) * 2) ^ swzr(b))) = f2bf(v1 * inv);
  } else {
    int i = (b - KC) * 2048 + t * 8;            // 32 blocks cover 512x128
    const float4* src = (const float4*)(conv_w + i);
    float4 a = src[0], c4 = src[1];
    int d = i >> 7, c0 = i & 127;
    int dch = d >> 6, dl = d & 63;
    uint4 w;
    w.x = f2bf2(a.x, a.y);   w.y = f2bf2(a.z, a.w);
    w.z = f2bf2(c4.x, c4.y); w.w = f2bf2(c4.z, c4.w);
    *(uint4*)((char*)Wsw + dch * 16384 + dl * 256 + ((c0 * 2) ^ swzr(dl))) = w;
  }
}

// ---------- fused xnorm + projection + logits/exp — counted-vmcnt loop (R18) ----------
__global__ __launch_bounds__(512, 2) void k_xproj(const float* __restrict__ x,
                                                  const unsigned short* __restrict__ Wsw,
                                                  const unsigned short* __restrict__ Cbsw,
                                                  const float* __restrict__ conv_b,
                                                  unsigned short* __restrict__ fT,
                                                  unsigned short* __restrict__ eg,
                                                  float* __restrict__ psums) {
  __shared__ __align__(16) char smem[67072];
  char* Xraw  = smem;                     // 128l x 256B: l*256 + ((c*2)^swzr(l))
  char* fbuf  = smem;                     // 128l x 128B (aliases Xraw lo, dead after hoist)
  char* etile = smem + 16384;             // aliases Xraw hi
  char* Ws    = smem + 32768;             // 64d x 256B
  char* Cb2   = smem + 49152;             // 2 x (64k x 128B)
  float* invb = (float*)(smem + 65536);   // [128]
  float* ps   = (float*)(smem + 66048);   // [64][4]
  int n = blockIdx.y, lblk = blockIdx.x, l0 = lblk * 128;
  int t = threadIdx.x, lane = t & 63, wid = t >> 6;

  // prologue: stage Ws(0) + Cbs(0)->buf0 (drained at B-P1's full syncthreads)
  #pragma unroll
  for (int q = 0; q < 2; q++)
    gll16((const char*)Wsw + (q * 8 + wid) * 1024 + lane * 16, Ws + (q * 8 + wid) * 1024);
  gll16((const char*)Cbsw + wid * 1024 + lane * 16, Cb2 + wid * 1024);

  // P1: x fp32 (c-pair rows) -> bf16 -> Xraw (l,c), u32 pair-writes
  #pragma unroll
  for (int j = 0; j < 2; j++) {
    int c0 = ((t >> 4) + 32 * j) * 2;
    const float4* r0p = (const float4*)(x + ((size_t)n * CD + c0) * HW + l0);
    const float4* r1p = (const float4*)(x + ((size_t)n * CD + c0 + 1) * HW + l0);
    #pragma unroll
    for (int jj = 0; jj < 2; jj++) {
      int f4 = (t & 15) + 16 * jj;
      float4 a = r0p[f4], b = r1p[f4];
      int lb = f4 * 4;
      *(unsigned*)(Xraw + (lb + 0) * 256 + ((c0 * 2) ^ swzr(lb + 0))) = f2bf2(a.x, b.x);
      *(unsigned*)(Xraw + (lb + 1) * 256 + ((c0 * 2) ^ swzr(lb + 1))) = f2bf2(a.y, b.y);
      *(unsigned*)(Xraw + (lb + 2) * 256 + ((c0 * 2) ^ swzr(lb + 2))) = f2bf2(a.z, b.z);
      *(unsigned*)(Xraw + (lb + 3) * 256 + ((c0 * 2) ^ swzr(lb + 3))) = f2bf2(a.w, b.w);
    }
  }
  __syncthreads();                        // B-P1 (full drain): Xraw ready; stage(0) done

  // P2: inv[l] from row sums (b128 reads; XOR permutation is sum-invariant)
  {
    int l = t >> 2;
    float ss = 0.f;
    #pragma unroll
    for (int p = 0; p < 4; p++) {
      int s16 = (t & 3) + 4 * p;
      bfrag v = *(const bfrag*)(Xraw + l * 256 + ((s16 * 16) ^ swzr(l)));
      #pragma unroll
      for (int i = 0; i < 8; i++) { float f = bf2f((unsigned short)v[i]); ss += f * f; }
    }
    ss += __shfl_xor(ss, 1); ss += __shfl_xor(ss, 2);
    if ((t & 3) == 0) invb[l] = 1.0f / fmaxf(sqrtf(ss), 1e-12f);
  }
  __syncthreads();                        // B-P2: invb ready

  int wd = wid & 1, wl = wid >> 1;        // f waves: 2(d-grp of 32) x 4(l-grp of 32)
  int er = wid >> 2, ec = wid & 3;        // e waves: 2(k-grp of 32) x 4(l-grp of 32)
  int r0 = (lane >> 4) << 2, cl = lane & 15;
  int hi8 = (lane >> 4) << 3;

  // hoist Xraw B-fragments (dch-invariant, 32 VGPR) + per-l-frag inv
  bfrag bfh[4][2];
  #pragma unroll
  for (int kk = 0; kk < 4; kk++)
    #pragma unroll
    for (int j = 0; j < 2; j++) {
      int row = wl * 32 + j * 16 + cl;
      int c0e = kk * 32 + hi8;
      bfh[kk][j] = *(const bfrag*)(Xraw + row * 256 + ((c0e * 2) ^ swzr(row)));
    }
  float hinv[2];
  #pragma unroll
  for (int j = 0; j < 2; j++) hinv[j] = invb[wl * 32 + j * 16 + cl];
  __syncthreads();                        // B-H: Xraw dead -> fbuf/etile usable; queue empty

  facc zero = {0.f, 0.f, 0.f, 0.f};
  facc e_acc[2][2];
  e_acc[0][0] = zero; e_acc[0][1] = zero; e_acc[1][0] = zero; e_acc[1][1] = zero;

  for (int dch = 0; dch < 8; dch++) {
    const char* Cbs = Cb2 + ((dch & 1) << 13);
    // f-MFMA: D[d][l], wave tile 32d x 32l
    facc acc[2][2];
    acc[0][0] = zero; acc[0][1] = zero; acc[1][0] = zero; acc[1][1] = zero;
    #pragma unroll
    for (int kk = 0; kk < 4; kk++) {
      int c0e = kk * 32 + hi8;
      bfrag am[2];
      #pragma unroll
      for (int m = 0; m < 2; m++) {
        int d = wd * 32 + m * 16 + cl;
        am[m] = *(const bfrag*)(Ws + d * 256 + ((c0e * 2) ^ swzr(d)));
      }
      #pragma unroll
      for (int m = 0; m < 2; m++)
        #pragma unroll
        for (int j = 0; j < 2; j++)
          acc[m][j] = __builtin_amdgcn_mfma_f32_16x16x32_bf16(am[m], bfh[kk][j], acc[m][j], 0, 0, 0);
    }
    // epilogue: f = inv[l]*acc + bias -> fbuf(l,d64); quad spans d -> b64 writes
    #pragma unroll
    for (int m = 0; m < 2; m++) {
      int d0 = wd * 32 + m * 16 + r0;
      float4 bq = *(const float4*)(conv_b + dch * 64 + d0);
      #pragma unroll
      for (int j = 0; j < 2; j++) {
        int l = wl * 32 + j * 16 + cl;
        uint2 w;
        w.x = f2bf2(acc[m][j][0] * hinv[j] + bq.x, acc[m][j][1] * hinv[j] + bq.y);
        w.y = f2bf2(acc[m][j][2] * hinv[j] + bq.z, acc[m][j][3] * hinv[j] + bq.w);
        *(uint2*)(fbuf + l * 128 + ((d0 * 2) ^ swzr(l))) = w;
      }
    }
    // B_mid: Cbs(dch) drained + fbuf visible; old stores stay in flight
    asm volatile("s_waitcnt vmcnt(2) lgkmcnt(0)" ::: "memory");
    __builtin_amdgcn_s_barrier();
    __builtin_amdgcn_sched_barrier(0);
    // stage Ws(dch+1) + Cbs(dch+1) (issue order pinned: stages before stores)
    if (dch < 7) {
      #pragma unroll
      for (int q = 0; q < 2; q++)
        gll16((const char*)Wsw + (dch + 1) * 16384 + (q * 8 + wid) * 1024 + lane * 16,
              Ws + (q * 8 + wid) * 1024);
      gll16((const char*)Cbsw + (dch + 1) * 8192 + wid * 1024 + lane * 16,
            Cb2 + (((dch + 1) & 1) << 13) + wid * 1024);
    }
    __builtin_amdgcn_sched_barrier(0);
    // coalesced fT dump (2 b128 ds_reads + 2 global stores; stores drain next iter)
    {
      #pragma unroll
      for (int p = 0; p < 2; p++) {
        int ch = p * 512 + t;
        int lr = ch >> 3, c16 = ch & 7;
        bfrag v = *(const bfrag*)(fbuf + lr * 128 + ((c16 * 16) ^ swzr(lr)));
        *(bfrag*)(fT + ((size_t)n * HW + l0 + lr) * DD + dch * 64 + c16 * 8) = v;
      }
    }
    // e-MFMA: e_acc += Cbs(64k x 64d) x fbuf(128l x 64d)^T, wave tile 32k x 32l
    #pragma unroll
    for (int kk = 0; kk < 2; kk++) {
      int d0 = kk * 32 + hi8;
      bfrag ca[2], fb[2];
      #pragma unroll
      for (int m2 = 0; m2 < 2; m2++) {
        int k2 = er * 32 + m2 * 16 + cl;
        ca[m2] = *(const bfrag*)(Cbs + k2 * 128 + ((d0 * 2) ^ swzr(k2)));
      }
      #pragma unroll
      for (int j2 = 0; j2 < 2; j2++) {
        int l2 = ec * 32 + j2 * 16 + cl;
        fb[j2] = *(const bfrag*)(fbuf + l2 * 128 + ((d0 * 2) ^ swzr(l2)));
      }
      #pragma unroll
      for (int m2 = 0; m2 < 2; m2++)
        #pragma unroll
        for (int j2 = 0; j2 < 2; j2++)
          e_acc[m2][j2] = __builtin_amdgcn_mfma_f32_16x16x32_bf16(ca[m2], fb[j2], e_acc[m2][j2], 0, 0, 0);
    }
    // B_top: fbuf reads done; Ws(dch+1) drained; stores from this iter stay
    asm volatile("s_waitcnt vmcnt(3) lgkmcnt(0)" ::: "memory");
    __builtin_amdgcn_s_barrier();
    __builtin_amdgcn_sched_barrier(0);
  }

  // P5: exp -> etile + rowsum partials
  {
    int l2base = ec * 32;
    #pragma unroll
    for (int m2 = 0; m2 < 2; m2++) {
      #pragma unroll
      for (int q = 0; q < 4; q++) {
        int k2 = er * 32 + m2 * 16 + r0 + q;
        float vsum = 0.f;
        #pragma unroll
        for (int j2 = 0; j2 < 2; j2++) {
          int l2 = l2base + j2 * 16 + cl;
          float ev = __expf(e_acc[m2][j2][q]);
          *(unsigned short*)(etile + (l2 >> 6) * 8192 + k2 * 128 +
                             (((l2 & 63) * 2) ^ swzr(k2))) = f2bf(ev);
          vsum += ev;
        }
        vsum += __shfl_xor(vsum, 1); vsum += __shfl_xor(vsum, 2);
        vsum += __shfl_xor(vsum, 4); vsum += __shfl_xor(vsum, 8);
        if (cl == 0) ps[k2 * 4 + ec] = vsum;
      }
    }
  }
  __syncthreads();                        // full drain before final dumps
  // dump 2 e-images (16K contiguous) + psums
  {
    size_t base = ((size_t)n * 64 + lblk * 2) * 8192;
    #pragma unroll
    for (int p = 0; p < 2; p++) {
      uint4 v = *(const uint4*)(etile + (t + p * 512) * 16);
      *(uint4*)((char*)eg + base + (t + p * 512) * 16) = v;
    }
  }
  if (t < 64) {
    float4 v = ((const float4*)ps)[t];
    psums[((size_t)n * 32 + lblk) * 64 + t] = v.x + v.y + v.z + v.w;
  }
}

// ---------- vlad partials: part[sk,n,k,d] = sum_l e[n,k,l] f[n,l,d] ----------
// R19: split-L 8 (grid 512, 2 blocks/CU), T14 reg-prefetch of fT B-tile,
// counted-vmcnt barriers (per-wave queue at mid: [A-gll16 x4, B' x8] -> vmcnt(8)).
__global__ __launch_bounds__(256, 2) void k_vlad(const unsigned short* __restrict__ eg,
                                                 const unsigned short* __restrict__ fT,
                                                 float* __restrict__ part) {
  __shared__ __align__(16) char smem[49152];
  char* As = smem;            // 2 images x [64k x 128B]: k*128 + ((l''*2)^swzr(k))
  char* Bs = smem + 16384;    // [128d][128l]: d*256 + ((l*2)^(((d&7)^((d>>3)&7))<<4))
  int t = threadIdx.x, lane = t & 63, wid = t >> 6;
  int wr = wid >> 1, wc = wid & 1;
  int lin = blockIdx.x;
  // XCD grouping: 4 dt-blocks of one (n,sk) land on the same XCD (e-chunk L2 reuse)
  int xcd = lin & 7, jj = lin >> 3;                // jj 0..63
  int grp = xcd * 16 + (jj >> 2);                  // 0..127 = (n,sk)
  int dt = jj & 3, n = grp >> 3, sk = grp & 7;
  int dbase = dt * 128;
  const unsigned short* fTb = fT + (size_t)n * HW * DD + dbase;
  facc acc[2][4];
  facc zero = {0.f, 0.f, 0.f, 0.f};
  #pragma unroll
  for (int m = 0; m < 2; m++)
    #pragma unroll
    for (int j = 0; j < 4; j++) acc[m][j] = zero;

  // prologue: prefetch B(0) into regs (latency exposed once)
  bfrag br[8];
  #pragma unroll
  for (int q = 0; q < 8; q++) {
    int ch = q * 256 + t;
    int l = ch >> 4, dc = ch & 15;
    br[q] = *(const bfrag*)(fTb + (size_t)(sk * 512 + l) * DD + dc * 8);
  }

  #pragma unroll
  for (int ks = 0; ks < 4; ks++) {
    int l0 = sk * 512 + ks * 128;
    // write Breg -> Bs (auto-waits on br loads: issued one iteration ago)
    #pragma unroll
    for (int q = 0; q < 8; q++) {
      int ch = q * 256 + t;
      int l = ch >> 4, dc = ch & 15;
      #pragma unroll
      for (int i = 0; i < 8; i++) {
        int d = dc * 8 + i;
        int swz = (((d & 7) ^ ((d >> 3) & 7)) << 4);
        *(unsigned short*)(Bs + d * 256 + ((l * 2) ^ swz)) = (unsigned short)br[q][i];
      }
    }
    __builtin_amdgcn_sched_barrier(0);
    // issue gll16 A(ks): two consecutive 8K e-images for this l-range
    {
      const char* easrc = (const char*)eg + ((size_t)n * 64 + (l0 >> 6)) * 8192;
      #pragma unroll
      for (int q = 0; q < 4; q++)
        gll16(easrc + (q * 4 + wid) * 1024 + lane * 16, As + (q * 4 + wid) * 1024);
    }
    __builtin_amdgcn_sched_barrier(0);
    // prefetch B(ks+1) (stays in flight across the mid barrier)
    if (ks < 3) {
      #pragma unroll
      for (int q = 0; q < 8; q++) {
        int ch = q * 256 + t;
        int l = ch >> 4, dc = ch & 15;
        br[q] = *(const bfrag*)(fTb + (size_t)(l0 + 128 + l) * DD + dc * 8);
      }
      asm volatile("s_waitcnt vmcnt(8) lgkmcnt(0)" ::: "memory");   // drain A, keep B'
    } else {
      asm volatile("s_waitcnt vmcnt(0) lgkmcnt(0)" ::: "memory");   // last iter: drain all
    }
    __builtin_amdgcn_s_barrier();
    __builtin_amdgcn_sched_barrier(0);
    // MFMA over As (2 images) x Bs
    #pragma unroll
    for (int kk = 0; kk < 128; kk += 32) {
      int lk = kk + ((lane >> 4) << 3);
      const char* Ai = As + (kk >> 6) * 8192;
      int ll = lk & 63;
      bfrag af[2], bf[4];
      #pragma unroll
      for (int m = 0; m < 2; m++) {
        int krow = wr * 32 + m * 16 + (lane & 15);
        af[m] = *(const bfrag*)(Ai + krow * 128 + ((ll * 2) ^ swzr(krow)));
      }
      #pragma unroll
      for (int j = 0; j < 4; j++) {
        int d = wc * 64 + j * 16 + (lane & 15);
        int swz = (((d & 7) ^ ((d >> 3) & 7)) << 4);
        bf[j] = *(const bfrag*)(Bs + d * 256 + ((lk * 2) ^ swz));
      }
      #pragma unroll
      for (int m = 0; m < 2; m++)
        #pragma unroll
        for (int j = 0; j < 4; j++)
          acc[m][j] = __builtin_amdgcn_mfma_f32_16x16x32_bf16(af[m], bf[j], acc[m][j], 0, 0, 0);
    }
    // end barrier: LDS reads done (As/Bs may be overwritten next iter); B' stays in flight
    asm volatile("s_waitcnt lgkmcnt(0)" ::: "memory");
    __builtin_amdgcn_s_barrier();
    __builtin_amdgcn_sched_barrier(0);
  }
  int r0 = (lane >> 4) << 2, cl = lane & 15;
  size_t base = ((size_t)(sk * NB + n)) * (KC * DD);
  #pragma unroll
  for (int m = 0; m < 2; m++) {
    int krow = wr * 32 + m * 16 + r0;
    #pragma unroll
    for (int j = 0; j < 4; j++) {
      int d = dbase + wc * 64 + j * 16 + cl;
      #pragma unroll
      for (int q = 0; q < 4; q++)
        part[base + (size_t)(krow + q) * DD + d] = acc[m][j][q];
    }
  }
}

// ---------- reduce split-K partials (8), compute rinv inline, normalize ----------
__global__ __launch_bounds__(256) void k_reduce(const float* __restrict__ part,
                                                const float* __restrict__ psums,
                                                float* __restrict__ out) {
  int b = blockIdx.x, t = threadIdx.x;
  int nk = b >> 1;                              // constant per block
  int n = nk >> 6, k = nk & 63;
  __shared__ float rsh;
  if (t < 32) {
    float s = psums[((size_t)n * 32 + t) * 64 + k];
    #pragma unroll
    for (int off = 16; off; off >>= 1) s += __shfl_xor(s, off, 32);
    if (t == 0) rsh = 1.0f / s;
  }
  __syncthreads();
  float rinv = rsh;
  int i = b * 256 + t;
  float s = 0.f;
  #pragma unroll
  for (int skk = 0; skk < 8; skk++) s += part[(size_t)skk * (NB * KC * DD) + i];
  out[i] = s * rinv;
}

extern "C" void kernel_launch(void* const* d_in, const int* in_sizes, int n_in,
                              void* d_out, int out_size, void* d_ws, size_t ws_size,
                              hipStream_t stream) {
  const float* x         = (const float*)d_in[0];
  const float* conv_w    = (const float*)d_in[1];
  const float* conv_b    = (const float*)d_in[2];
  const float* centroids = (const float*)d_in[3];
  float* out = (float*)d_out;
  char* ws = (char*)d_ws;

  // ws layout (bytes):
  //   Wsw   @ 0          (128 KB)   conv_w bf16, 8x16K pre-swizzled images
  //   Cbsw  @ 131072     (64 KB)    normalized centroids bf16, 8x8K images
  //   fT    @ 196608     (64 MB)    f bf16 (N,L,D)
  //   eg    @ 67305472   (8 MB)     exp(logits) bf16, N*64 x 8K images
  //   psums @ 75694080   (128 KB)   per-tile row sums fp32 (N,32,K)
  //   part  @ 75960320   (16 MB)    vlad partials fp32 (8,N,K,D)
  unsigned short* Wsw  = (unsigned short*)(ws);
  unsigned short* Cbsw = (unsigned short*)(ws + 131072);
  unsigned short* fT   = (unsigned short*)(ws + 196608);
  unsigned short* eg   = (unsigned short*)(ws + 67305472ull);
  float*          psums= (float*)(ws + 75694080ull);
  float*          part = (float*)(ws + 75960320ull);

  k_prep<<<dim3(96), dim3(256), 0, stream>>>(conv_w, centroids, Wsw, Cbsw);

  // fused xnorm + projection + logits/exp -> fT, e-images, psums
  k_xproj<<<dim3(32, NB), dim3(512), 0, stream>>>(x, Wsw, Cbsw, conv_b, fT, eg, psums);

  // vlad partials: e(K,L) * f(L,D), split-L into 8 chunks of 512
  k_vlad<<<dim3(512), dim3(256), 0, stream>>>(eg, fT, part);

  k_reduce<<<dim3(NB * KC * DD / 256), dim3(256), 0, stream>>>(part, psums, out);

  (void)in_sizes; (void)n_in; (void)out_size; (void)ws_size;
}